// Round 3
// baseline (42.402 us; speedup 1.0000x reference)
//
#include <hip/hip_runtime.h>

// Problem constants (match reference)
#define BATCH 16
#define IMG_H 1024
#define IMG_W 1024
#define WORDS 16            // 1024 cols / 64 bits
#define TY 32               // output rows per block
#define SROWS (TY + 8)      // staged rows incl. +-4 halo = 40
#define NT 1024             // threads per block (16 waves)
#define NWAVES (NT / 64)

typedef unsigned long long u64;

__global__ void wbce_zero_kernel(float* out) { out[0] = 0.0f; }

// __launch_bounds__(1024, 8): 8 waves/EU min -> 2 blocks/CU, VGPR capped at 64
__global__ __launch_bounds__(NT, 8)
void wbce_kernel(const float* __restrict__ logits,
                 const float* __restrict__ targets,
                 float* __restrict__ out)
{
    __shared__ u64 sT [SROWS * WORDS];   // packed targets (halo rows included)
    __shared__ u64 sHD[SROWS * WORDS];   // horizontal 9-dilate (OR)
    __shared__ u64 sHE[SROWS * WORDS];   // horizontal 9-erode  (AND)
    __shared__ u64 sBnd[TY * WORDS];     // boundary bits = dil & ~ero
    __shared__ float sRed[NWAVES];

    const int tid  = threadIdx.x;
    const int lane = tid & 63;
    const int wv   = tid >> 6;
    const int rowBase = blockIdx.x * TY;
    const int b = blockIdx.y;

    const float* tgt = targets + (size_t)b * (IMG_H * IMG_W);
    const float* lg  = logits  + (size_t)b * (IMG_H * IMG_W);

    // ---- Prefetch ALL logits this thread needs (32 px = 8 x float4).
    // Issued before the target loads so both streams occupy the memory
    // system concurrently; the vmcnt(0) drain at the first barrier makes
    // them free to consume in phase C.
    float4 x[8];
    #pragma unroll
    for (int k = 0; k < 8; ++k) {
        int it  = tid + k * NT;
        int r   = it >> 8;          // 256 float4s per row
        int pos = it & 255;
        x[k] = *(const float4*)(lg + (size_t)(rowBase + r) * IMG_W + pos * 4);
    }

    // ---- Phase A: pack targets via ballot, 4 words per wave-iter (MLP=4) ----
    for (int it4 = wv * 4; it4 < SROWS * WORDS; it4 += NWAVES * 4) {
        int sr = it4 >> 4;              // (it4&15) in {0,4,8,12}: no row straddle
        int gr = rowBase + sr - 4;
        float v0 = 0.f, v1 = 0.f, v2 = 0.f, v3 = 0.f;
        if (gr >= 0 && gr < IMG_H) {    // wave-uniform branch
            const float* rp = tgt + (size_t)gr * IMG_W + ((it4 & 15) * 64) + lane;
            v0 = rp[0]; v1 = rp[64]; v2 = rp[128]; v3 = rp[192];
        }
        u64 m0 = __ballot(v0 > 0.5f);
        u64 m1 = __ballot(v1 > 0.5f);
        u64 m2 = __ballot(v2 > 0.5f);
        u64 m3 = __ballot(v3 > 0.5f);
        if (lane == 0) {
            sT[it4]     = m0; sT[it4 + 1] = m1;
            sT[it4 + 2] = m2; sT[it4 + 3] = m3;
        }
    }
    // Pin the prefetched values here so hipcc cannot sink the loads past the
    // barrier into phase C (barrier drains vmcnt(0) anyway -> no extra cost).
    #pragma unroll
    for (int k = 0; k < 8; ++k)
        asm volatile("" : "+v"(x[k].x), "+v"(x[k].y), "+v"(x[k].z), "+v"(x[k].w));
    __syncthreads();

    // ---- Phase B: horizontal +-4 bitwise OR/AND, one thread per word ----
    for (int it = tid; it < SROWS * WORDS; it += NT) {
        int sr = it >> 4;
        int w  = it & 15;
        int gr = rowBase + sr - 4;
        u64 hd, he;
        if (gr < 0 || gr >= IMG_H) {
            hd = 0ULL;       // OOB row: neutral for vertical OR
            he = ~0ULL;      // OOB row: neutral for vertical AND
        } else {
            u64 C  = sT[it];
            u64 P  = (w > 0)  ? sT[it - 1] : 0ULL;
            u64 N  = (w < 15) ? sT[it + 1] : 0ULL;
            u64 Pe = (w > 0)  ? P : ~0ULL;
            u64 Ne = (w < 15) ? N : ~0ULL;
            u64 d = C, e = C;
            #pragma unroll
            for (int s = 1; s <= 4; ++s) {
                d |= (C >> s) | (N  << (64 - s));
                d |= (C << s) | (P  >> (64 - s));
                e &= (C >> s) | (Ne << (64 - s));
                e &= (C << s) | (Pe >> (64 - s));
            }
            hd = d; he = e;
        }
        sHD[it] = hd;
        sHE[it] = he;
    }
    __syncthreads();

    // ---- Phase B2: vertical 9-row OR/AND -> boundary bits ----
    for (int it = tid; it < TY * WORDS; it += NT) {
        int r = it >> 4;
        int w = it & 15;
        u64 d = 0ULL, e = ~0ULL;
        #pragma unroll
        for (int k = 0; k < 9; ++k) {
            d |= sHD[(r + k) * WORDS + w];
            e &= sHE[(r + k) * WORDS + w];
        }
        sBnd[it] = d & ~e;
    }
    __syncthreads();

    // ---- Phase C: fused BCE from prefetched registers + boundary bits ----
    float acc = 0.0f;
    #pragma unroll
    for (int k = 0; k < 8; ++k) {
        int it  = tid + k * NT;
        int r   = it >> 8;
        int pos = it & 255;
        int w   = pos >> 4;         // word index
        int sh  = (pos & 15) * 4;   // bit offset within word

        unsigned int bb = (unsigned int)(sBnd[r * WORDS + w] >> sh);
        unsigned int tb = (unsigned int)(sT[(r + 4) * WORDS + w] >> sh);

        const float xs[4] = {x[k].x, x[k].y, x[k].z, x[k].w};
        #pragma unroll
        for (int j = 0; j < 4; ++j) {
            float xv = xs[j];
            float wg = 1.0f + 2.0f * (float)((bb >> j) & 1u);   // BOUNDARY_WEIGHT=3
            float y  = (float)((tb >> j) & 1u);
            float a  = fabsf(xv);
            float t  = __builtin_exp2f(a * -1.44269504088896340736f);
            float sp = __builtin_log2f(1.0f + t) * 0.69314718055994530942f;
            float pe = fmaxf(xv, 0.0f) - xv * y + sp;
            acc = fmaf(wg, pe, acc);
        }
    }

    // ---- block reduction: wave64 shuffle tree, cross-wave via LDS ----
    #pragma unroll
    for (int off = 32; off > 0; off >>= 1)
        acc += __shfl_down(acc, off, 64);
    if (lane == 0) sRed[wv] = acc;
    __syncthreads();
    if (tid == 0) {
        float s = 0.0f;
        #pragma unroll
        for (int i = 0; i < NWAVES; ++i) s += sRed[i];
        atomicAdd(out, s * (1.0f / 16777216.0f));   // mean: 1/2^24 exact
    }
}

extern "C" void kernel_launch(void* const* d_in, const int* in_sizes, int n_in,
                              void* d_out, int out_size, void* d_ws, size_t ws_size,
                              hipStream_t stream) {
    const float* logits  = (const float*)d_in[0];
    const float* targets = (const float*)d_in[1];
    float* out = (float*)d_out;

    // d_out is poisoned before timing and not re-poisoned between replays:
    // zero it every call (graph-capturable kernel, same stream).
    wbce_zero_kernel<<<dim3(1), dim3(1), 0, stream>>>(out);

    dim3 grid(IMG_H / TY, BATCH);   // 32 x 16 = 512 blocks, 16 waves each
    dim3 block(NT);
    wbce_kernel<<<grid, block, 0, stream>>>(logits, targets, out);
}

// Round 4
// 42.138 us; speedup vs baseline: 1.0063x; 1.0063x over previous
//
#include <hip/hip_runtime.h>

// Problem constants (match reference)
#define BATCH 16
#define IMG_H 1024
#define IMG_W 1024
#define WORDS 16            // 1024 cols / 64 bits
typedef unsigned long long u64;

// ============ kernel 0: zero the output accumulator ============
__global__ void wbce_zero_kernel(float* out) { out[0] = 0.0f; }

// ============ kernel 1: pack targets -> bitmask (pure stream) ============
// total words = 16*1024*16 = 262144; processed in groups of 4 words per
// wave-iter. 2048 blocks x 4 waves = 8192 waves, 8 iters each.
#define PK_NT 256
#define PK_BLOCKS 2048
__global__ __launch_bounds__(PK_NT, 8)
void wbce_pack_kernel(const float* __restrict__ tgt, u64* __restrict__ pak)
{
    const int lane = threadIdx.x & 63;
    const int gw   = blockIdx.x * (PK_NT / 64) + (threadIdx.x >> 6);
    #pragma unroll
    for (int i = 0; i < 8; ++i) {
        int g = gw + i * (PK_BLOCKS * (PK_NT / 64));   // word-group id [0,65536)
        const float* p = tgt + (size_t)g * 256 + lane; // 4 words = 256 px, row-aligned
        float v0 = p[0], v1 = p[64], v2 = p[128], v3 = p[192];
        u64 m0 = __ballot(v0 > 0.5f);
        u64 m1 = __ballot(v1 > 0.5f);
        u64 m2 = __ballot(v2 > 0.5f);
        u64 m3 = __ballot(v3 > 0.5f);
        if (lane == 0) {
            ulonglong2* q = (ulonglong2*)(pak + (size_t)g * 4);
            q[0] = make_ulonglong2(m0, m1);
            q[1] = make_ulonglong2(m2, m3);
        }
    }
}

// ============ kernel 2: bit-morphology (tiny) + BCE stream + reduce ============
#define BC_NT 512
#define TY 16
#define SR (TY + 8)         // 24 staged rows (+-4 halo)
#define NWAVES (BC_NT / 64)

__global__ __launch_bounds__(BC_NT, 8)
void wbce_bce_kernel(const float* __restrict__ logits,
                     const u64* __restrict__ pak,
                     float* __restrict__ out)
{
    __shared__ u64 sPak[SR * WORDS];    // packed target words (halo rows)
    __shared__ u64 sHD [SR * WORDS];    // horizontal 9-dilate
    __shared__ u64 sHE [SR * WORDS];    // horizontal 9-erode
    __shared__ u64 sBnd[TY * WORDS];    // boundary bits
    __shared__ float sRed[NWAVES];

    const int tid  = threadIdx.x;
    const int lane = tid & 63;
    const int wv   = tid >> 6;
    const int rowBase = blockIdx.x * TY;
    const int b = blockIdx.y;

    const u64*  pb = pak    + (size_t)b * (IMG_H * WORDS);
    const float* lg = logits + (size_t)b * (IMG_H * IMG_W);

    // ---- phase AB: load packed words (L2-hot, 3KB) + horizontal OR/AND ----
    if (tid < SR * WORDS) {
        int sr = tid >> 4, w = tid & 15;
        int gr = rowBase + sr - 4;
        u64 hd = 0ULL, he = ~0ULL, C = 0ULL;   // OOB row: neutral for vertical
        if (gr >= 0 && gr < IMG_H) {
            const u64* rp = pb + (size_t)gr * WORDS;
            C = rp[w];
            u64 P  = (w > 0)  ? rp[w - 1] : 0ULL;   // OOB col fill: dilate=0
            u64 N  = (w < 15) ? rp[w + 1] : 0ULL;
            u64 Pe = (w > 0)  ? P : ~0ULL;          // OOB col fill: erode=1
            u64 Ne = (w < 15) ? N : ~0ULL;
            u64 d = C, e = C;
            #pragma unroll
            for (int s = 1; s <= 4; ++s) {
                d |= (C >> s) | (N  << (64 - s));
                d |= (C << s) | (P  >> (64 - s));
                e &= (C >> s) | (Ne << (64 - s));
                e &= (C << s) | (Pe >> (64 - s));
            }
            hd = d; he = e;
        }
        sPak[tid] = C;
        sHD[tid]  = hd;
        sHE[tid]  = he;
    }
    __syncthreads();

    // ---- phase B2: vertical 9-row OR/AND -> boundary bits ----
    if (tid < TY * WORDS) {
        int r = tid >> 4, w = tid & 15;
        u64 d = 0ULL, e = ~0ULL;
        #pragma unroll
        for (int k = 0; k < 9; ++k) {
            d |= sHD[(r + k) * WORDS + w];
            e &= sHE[(r + k) * WORDS + w];
        }
        sBnd[tid] = d & ~e;
    }
    __syncthreads();

    // ---- phase C: stream logits (64KB/block), fused BCE ----
    float acc = 0.0f;
    #pragma unroll
    for (int k = 0; k < (TY * IMG_W / 4) / BC_NT; ++k) {   // 8 iters
        int it  = tid + k * BC_NT;
        int r   = it >> 8;          // 256 float4 per row
        int pos = it & 255;
        int w   = pos >> 4;
        int sh  = (pos & 15) * 4;

        float4 x4 = *(const float4*)(lg + (size_t)(rowBase + r) * IMG_W + pos * 4);
        unsigned int bb = (unsigned int)(sBnd[r * WORDS + w] >> sh);
        unsigned int tb = (unsigned int)(sPak[(r + 4) * WORDS + w] >> sh);

        const float xs[4] = {x4.x, x4.y, x4.z, x4.w};
        #pragma unroll
        for (int j = 0; j < 4; ++j) {
            float x  = xs[j];
            float wg = 1.0f + 2.0f * (float)((bb >> j) & 1u);   // BOUNDARY_WEIGHT=3
            float y  = (float)((tb >> j) & 1u);
            float a  = fabsf(x);
            float t  = __builtin_exp2f(a * -1.44269504088896340736f);
            float sp = __builtin_log2f(1.0f + t) * 0.69314718055994530942f;
            float pe = fmaxf(x, 0.0f) - x * y + sp;
            acc = fmaf(wg, pe, acc);
        }
    }

    // ---- block reduction: wave64 shuffle tree, cross-wave via LDS ----
    #pragma unroll
    for (int off = 32; off > 0; off >>= 1)
        acc += __shfl_down(acc, off, 64);
    if (lane == 0) sRed[wv] = acc;
    __syncthreads();
    if (tid == 0) {
        float s = 0.0f;
        #pragma unroll
        for (int i = 0; i < NWAVES; ++i) s += sRed[i];
        atomicAdd(out, s * (1.0f / 16777216.0f));   // mean: 1/2^24 exact
    }
}

extern "C" void kernel_launch(void* const* d_in, const int* in_sizes, int n_in,
                              void* d_out, int out_size, void* d_ws, size_t ws_size,
                              hipStream_t stream) {
    const float* logits  = (const float*)d_in[0];
    const float* targets = (const float*)d_in[1];
    float* out = (float*)d_out;
    u64* pak = (u64*)d_ws;   // needs 16*1024*16*8 = 2 MiB of scratch

    // d_out is poisoned before timing and not re-poisoned between replays:
    // zero it every call (graph-capturable kernel, same stream).
    wbce_zero_kernel<<<dim3(1), dim3(1), 0, stream>>>(out);

    // 1) pack targets into bitmask words (pure stream, 67MB -> 2MB)
    wbce_pack_kernel<<<dim3(PK_BLOCKS), dim3(PK_NT), 0, stream>>>(targets, pak);

    // 2) bitwise morphology (L2-hot) + BCE stream + global reduce
    dim3 grid(IMG_H / TY, BATCH);   // 64 x 16 = 1024 blocks
    wbce_bce_kernel<<<grid, dim3(BC_NT), 0, stream>>>(logits, pak, out);
}

// Round 5
// 37.503 us; speedup vs baseline: 1.1306x; 1.1236x over previous
//
#include <hip/hip_runtime.h>

// Problem constants (match reference)
#define BATCH 16
#define IMG_H 1024
#define IMG_W 1024
#define WORDS 16            // 1024 cols / 64 bits
#define TY 32               // output rows per block
#define SROWS (TY + 8)      // 40 staged rows (+-4 halo)
#define NT 512              // 8 waves
#define NWAVES (NT / 64)

typedef unsigned long long u64;

__global__ void wbce_zero_kernel(float* out) { out[0] = 0.0f; }

// (512,4): min 4 waves/EU -> 2 blocks/CU (16 waves/CU), VGPR cap 128.
// The VGPR headroom is the point: phase C keeps 8 float4 live (double
// buffer) so each thread has 64B of loads in flight.
__global__ __launch_bounds__(NT, 4)
void wbce_kernel(const float* __restrict__ logits,
                 const float* __restrict__ targets,
                 float* __restrict__ out)
{
    __shared__ u64 sT [SROWS * WORDS];   // packed targets (halo rows)
    __shared__ u64 sHD[SROWS * WORDS];   // horizontal 9-dilate
    __shared__ u64 sHE[SROWS * WORDS];   // horizontal 9-erode
    __shared__ u64 sBnd[TY * WORDS];     // boundary bits
    __shared__ float sRed[NWAVES];

    const int tid  = threadIdx.x;
    const int lane = tid & 63;
    const int wv   = tid >> 6;
    const int rowBase = blockIdx.x * TY;
    const int b = blockIdx.y;

    const float* tgt = targets + (size_t)b * (IMG_H * IMG_W);
    const float* lg  = logits  + (size_t)b * (IMG_H * IMG_W);

    // ---- Phase A: ballot-pack targets, 4 words (1KB) per wave-iter ----
    for (int it4 = wv * 4; it4 < SROWS * WORDS; it4 += NWAVES * 4) {
        int sr = it4 >> 4;              // (it4&15) in {0,4,8,12}: no row straddle
        int gr = rowBase + sr - 4;
        float v0 = 0.f, v1 = 0.f, v2 = 0.f, v3 = 0.f;
        if (gr >= 0 && gr < IMG_H) {    // wave-uniform branch
            const float* rp = tgt + (size_t)gr * IMG_W + ((it4 & 15) * 64) + lane;
            v0 = rp[0]; v1 = rp[64]; v2 = rp[128]; v3 = rp[192];
        }
        u64 m0 = __ballot(v0 > 0.5f);
        u64 m1 = __ballot(v1 > 0.5f);
        u64 m2 = __ballot(v2 > 0.5f);
        u64 m3 = __ballot(v3 > 0.5f);
        if (lane == 0) {
            sT[it4]     = m0; sT[it4 + 1] = m1;
            sT[it4 + 2] = m2; sT[it4 + 3] = m3;
        }
    }
    __syncthreads();

    // ---- Phase B: horizontal +-4 bitwise OR/AND (640 words, 2 iters) ----
    for (int it = tid; it < SROWS * WORDS; it += NT) {
        int sr = it >> 4;
        int w  = it & 15;
        int gr = rowBase + sr - 4;
        u64 hd = 0ULL, he = ~0ULL;      // OOB row: neutral for vertical pass
        if (gr >= 0 && gr < IMG_H) {
            u64 C  = sT[it];
            u64 P  = (w > 0)  ? sT[it - 1] : 0ULL;   // OOB col: dilate fill 0
            u64 N  = (w < 15) ? sT[it + 1] : 0ULL;
            u64 Pe = (w > 0)  ? P : ~0ULL;           // OOB col: erode fill 1
            u64 Ne = (w < 15) ? N : ~0ULL;
            u64 d = C, e = C;
            #pragma unroll
            for (int s = 1; s <= 4; ++s) {
                d |= (C >> s) | (N  << (64 - s));
                d |= (C << s) | (P  >> (64 - s));
                e &= (C >> s) | (Ne << (64 - s));
                e &= (C << s) | (Pe >> (64 - s));
            }
            hd = d; he = e;
        }
        sHD[it] = hd;
        sHE[it] = he;
    }
    __syncthreads();

    // ---- Phase B2: vertical 9-row OR/AND (512 words = 1/thread) ----
    {
        int r = tid >> 4, w = tid & 15;
        u64 d = 0ULL, e = ~0ULL;
        #pragma unroll
        for (int k = 0; k < 9; ++k) {
            d |= sHD[(r + k) * WORDS + w];
            e &= sHE[(r + k) * WORDS + w];
        }
        sBnd[tid] = d & ~e;
    }
    __syncthreads();

    // ---- Phase C: stream logits with register double-buffer ----
    // 32 rows x 256 float4 = 8192 float4 / 512 thr = 16/thread, 4 batches.
    const float4* base = (const float4*)(lg + (size_t)rowBase * IMG_W);
    const unsigned* sBnd32 = (const unsigned*)sBnd;
    const unsigned* sT32   = (const unsigned*)sT;

    float acc = 0.0f;
    float4 bufA[4], bufB[4];
    #pragma unroll
    for (int j = 0; j < 4; ++j) bufA[j] = base[tid + j * NT];

    #pragma unroll
    for (int kb = 0; kb < 4; ++kb) {
        float4* cur = (kb & 1) ? bufB : bufA;
        float4* nxt = (kb & 1) ? bufA : bufB;
        if (kb < 3) {
            #pragma unroll
            for (int j = 0; j < 4; ++j)
                nxt[j] = base[tid + ((kb + 1) * 4 + j) * NT];
        }
        #pragma unroll
        for (int j = 0; j < 4; ++j) {
            int it  = tid + (kb * 4 + j) * NT;
            int r   = it >> 8;           // 256 float4 per row
            int pos = it & 255;
            int wi  = r * WORDS + (pos >> 4);
            int hf  = (pos >> 3) & 1;    // which u32 half of the u64 word
            int sh  = (pos & 7) * 4;     // 4-bit field, never crosses u32
            unsigned bbw = sBnd32[wi * 2 + hf];
            unsigned tbw = sT32[(wi + 4 * WORDS) * 2 + hf];   // row r+4

            const float xs[4] = {cur[j].x, cur[j].y, cur[j].z, cur[j].w};
            #pragma unroll
            for (int jj = 0; jj < 4; ++jj) {
                unsigned tb = (tbw >> (sh + jj)) & 1u;
                unsigned bb = (bbw >> (sh + jj)) & 1u;
                unsigned xu = __float_as_uint(xs[jj]);
                // pe = softplus((1-2y)x) = max(sgn,0)+ln2*log2(1+2^(-|x|*log2e))
                float sgn = __uint_as_float(xu ^ (tb << 31));
                float a   = __uint_as_float(xu & 0x7fffffffu);
                float t   = __builtin_exp2f(a * -1.44269504088896340736f);
                float l2  = __builtin_log2f(1.0f + t);
                float pe  = fmaf(l2, 0.69314718055994530942f, fmaxf(sgn, 0.0f));
                float wg  = fmaf((float)bb, 2.0f, 1.0f);   // BOUNDARY_WEIGHT=3
                acc = fmaf(wg, pe, acc);
            }
        }
    }

    // ---- block reduction: wave64 shuffle tree, cross-wave via LDS ----
    #pragma unroll
    for (int off = 32; off > 0; off >>= 1)
        acc += __shfl_down(acc, off, 64);
    if (lane == 0) sRed[wv] = acc;
    __syncthreads();
    if (tid == 0) {
        float s = 0.0f;
        #pragma unroll
        for (int i = 0; i < NWAVES; ++i) s += sRed[i];
        atomicAdd(out, s * (1.0f / 16777216.0f));   // mean: 1/2^24 exact
    }
}

extern "C" void kernel_launch(void* const* d_in, const int* in_sizes, int n_in,
                              void* d_out, int out_size, void* d_ws, size_t ws_size,
                              hipStream_t stream) {
    const float* logits  = (const float*)d_in[0];
    const float* targets = (const float*)d_in[1];
    float* out = (float*)d_out;

    // d_out is poisoned before timing and not re-poisoned between replays:
    // zero it every call (graph-capturable kernel, same stream).
    wbce_zero_kernel<<<dim3(1), dim3(1), 0, stream>>>(out);

    dim3 grid(IMG_H / TY, BATCH);   // 32 x 16 = 512 blocks, 8 waves each
    dim3 block(NT);
    wbce_kernel<<<grid, block, 0, stream>>>(logits, targets, out);
}